// Round 3
// baseline (1347.854 us; speedup 1.0000x reference)
//
#include <hip/hip_runtime.h>
#include <type_traits>

#define N_NODES 100000
#define N_EDGES 1600000
#define NFEAT 512
#define NHID 256
#define NCLASS 40
#define NPAD 100096   // 391 * 256
#define NB 391

typedef __bf16 bf16;
typedef __bf16 bf16x8 __attribute__((ext_vector_type(8)));
typedef float f32x4 __attribute__((ext_vector_type(4)));

// ---------------- CSR build ----------------

__global__ void init_cnt(int* cnt) {
    int i = blockIdx.x * 256 + threadIdx.x;
    if (i < NPAD) cnt[i] = 0;
}

__global__ void count_edges(const int* __restrict__ rows, int* __restrict__ cnt) {
    int e = blockIdx.x * 256 + threadIdx.x;
    if (e < N_EDGES) atomicAdd(&cnt[rows[e]], 1);
}

__global__ void reduce_blocks(const int* __restrict__ cnt, int* __restrict__ bsum) {
    __shared__ int sh[256];
    int t = threadIdx.x;
    sh[t] = cnt[blockIdx.x * 256 + t];
    __syncthreads();
    for (int off = 128; off > 0; off >>= 1) {
        if (t < off) sh[t] += sh[t + off];
        __syncthreads();
    }
    if (t == 0) bsum[blockIdx.x] = sh[0];
}

__global__ void scan_bsums(int* bsum) {
    __shared__ int sh[512];
    int t = threadIdx.x;
    int v = (t < NB) ? bsum[t] : 0;
    sh[t] = v;
    __syncthreads();
    for (int off = 1; off < 512; off <<= 1) {
        int x = (t >= off) ? sh[t - off] : 0;
        __syncthreads();
        sh[t] += x;
        __syncthreads();
    }
    if (t < NB) bsum[t] = sh[t] - v;  // exclusive
}

__global__ void scan_write(const int* __restrict__ cnt, const int* __restrict__ bsum,
                           int* __restrict__ rowptr, int* __restrict__ cursor,
                           float* __restrict__ dinv) {
    __shared__ int sh[256];
    int t = threadIdx.x, b = blockIdx.x;
    int i = b * 256 + t;
    int v = cnt[i];
    sh[t] = v;
    __syncthreads();
    for (int off = 1; off < 256; off <<= 1) {
        int x = (t >= off) ? sh[t - off] : 0;
        __syncthreads();
        sh[t] += x;
        __syncthreads();
    }
    int rp = bsum[b] + sh[t] - v;  // exclusive prefix
    rowptr[i] = rp;
    if (i < N_NODES) {
        cursor[i] = rp;
        dinv[i] = 1.0f / (float)(v + 1);  // +1 self-loop
    }
}

// row-range-filtered scatter: writes confined to ~1.6MB colidx window -> stays
// L2-resident per XCD, fewer partial-line writebacks
__global__ void scatter_edges_range(const int* __restrict__ rows, const int* __restrict__ cols,
                                    int* __restrict__ cursor, int* __restrict__ colidx,
                                    int lo, int hi) {
    int e = blockIdx.x * 256 + threadIdx.x;
    if (e < N_EDGES) {
        int r = rows[e];
        if (r >= lo && r < hi) {
            int pos = atomicAdd(&cursor[r], 1);
            colidx[pos] = cols[e];
        }
    }
}

// ---------------- weight conversion ----------------

__global__ void cvt_f2b(const float* __restrict__ a, bf16* __restrict__ b, int n) {
    int i = blockIdx.x * 256 + threadIdx.x;
    if (i < n) b[i] = (bf16)a[i];
}

__global__ void pad_w3(const float* __restrict__ W3, const float* __restrict__ b3,
                       bf16* __restrict__ W3p, float* __restrict__ b3p) {
    int i = blockIdx.x * 256 + threadIdx.x;  // over 64*256
    int r = i >> 8;
    W3p[i] = (bf16)((r < NCLASS) ? W3[(size_t)r * 256 + (i & 255)] : 0.f);
    if (i < 64) b3p[i] = (i < NCLASS) ? b3[i] : 0.f;
}

// ---------------- bf16 MFMA GEMM-NT ----------------
// C[M,Nout] = A[M,K] @ B[Nout,K]^T + bias, A fp32 or bf16 (converted in staging),
// B bf16. OUTMODE 0: bf16 out. OUTMODE 1: dual fp32 [M,40] + bf16 [M,64] padded.

template <int BN, typename AT, bool RELU, int OUTMODE>
__global__ __launch_bounds__(256) void gemm_mfma(const AT* __restrict__ A,
                                                 const bf16* __restrict__ B,
                                                 const float* __restrict__ bias,
                                                 bf16* __restrict__ Cb,
                                                 float* __restrict__ Cf,
                                                 bf16* __restrict__ Cpad,
                                                 int M, int K, int Nout) {
    constexpr int LDT = 56;                      // padded LDS row (bf16)
    constexpr int WTM = (BN == 128) ? 64 : 32;   // wave tile M
    constexpr int MI = WTM / 16;
    constexpr int WMC = 128 / WTM;               // waves along M
    __shared__ bf16 As[128 * LDT];
    __shared__ bf16 Bs[BN * LDT];

    int tid = threadIdx.x;
    int wave = tid >> 6, lane = tid & 63;
    int waveM = wave % WMC, waveN = wave / WMC;
    int lc = lane & 15, lq = lane >> 4;

    f32x4 acc[MI][4];
#pragma unroll
    for (int i = 0; i < MI; i++)
#pragma unroll
        for (int j = 0; j < 4; j++) acc[i][j] = (f32x4){0.f, 0.f, 0.f, 0.f};

    int sr = tid >> 2;           // staging row base
    int sc = (tid & 3) * 8;      // staging col (8 bf16)

    for (int k0 = 0; k0 < K; k0 += 32) {
        // stage A: 128 x 32
#pragma unroll
        for (int g = 0; g < 2; g++) {
            int r = sr + g * 64;
            int grow = blockIdx.y * 128 + r;
            bf16x8 val = (bf16x8){};
            if (grow < M) {
                if constexpr (std::is_same<AT, float>::value) {
                    const float* ap = A + (size_t)grow * K + k0 + sc;
                    float4 p0 = *(const float4*)ap;
                    float4 p1 = *(const float4*)(ap + 4);
                    val[0] = (bf16)p0.x; val[1] = (bf16)p0.y; val[2] = (bf16)p0.z; val[3] = (bf16)p0.w;
                    val[4] = (bf16)p1.x; val[5] = (bf16)p1.y; val[6] = (bf16)p1.z; val[7] = (bf16)p1.w;
                } else {
                    val = *(const bf16x8*)(A + (size_t)grow * K + k0 + sc);
                }
            }
            *(bf16x8*)&As[r * LDT + sc] = val;
        }
        // stage B
#pragma unroll
        for (int g = 0; g < BN / 64; g++) {
            int r = sr + g * 64;
            int brow = blockIdx.x * BN + r;
            *(bf16x8*)&Bs[r * LDT + sc] = *(const bf16x8*)(B + (size_t)brow * K + k0 + sc);
        }
        __syncthreads();

        bf16x8 af[MI], bfr[4];
#pragma unroll
        for (int i = 0; i < MI; i++)
            af[i] = *(const bf16x8*)&As[(waveM * WTM + i * 16 + lc) * LDT + lq * 8];
#pragma unroll
        for (int j = 0; j < 4; j++)
            bfr[j] = *(const bf16x8*)&Bs[(waveN * 64 + j * 16 + lc) * LDT + lq * 8];
#pragma unroll
        for (int i = 0; i < MI; i++)
#pragma unroll
            for (int j = 0; j < 4; j++)
                acc[i][j] = __builtin_amdgcn_mfma_f32_16x16x32_bf16(af[i], bfr[j], acc[i][j], 0, 0, 0);
        __syncthreads();
    }

    // epilogue
#pragma unroll
    for (int i = 0; i < MI; i++) {
        int row0 = blockIdx.y * 128 + waveM * WTM + i * 16 + lq * 4;
#pragma unroll
        for (int j = 0; j < 4; j++) {
            int colL = waveN * 64 + j * 16 + lc;
            int col = blockIdx.x * BN + colL;
            float bv = bias[col];
#pragma unroll
            for (int reg = 0; reg < 4; reg++) {
                int rr = row0 + reg;
                if (rr < M) {
                    float v = acc[i][j][reg] + bv;
                    if (RELU) v = v > 0.f ? v : 0.f;
                    if (OUTMODE == 0) {
                        Cb[(size_t)rr * Nout + col] = (bf16)v;
                    } else {
                        if (col < NCLASS) Cf[(size_t)rr * NCLASS + col] = v;
                        Cpad[(size_t)rr * 64 + col] = (bf16)v;
                    }
                }
            }
        }
    }
}

// ---------------- power-iteration SpMM (bf16 v padded to 64), unroll 8 ----------------

__global__ __launch_bounds__(256) void spmm_b(const bf16* __restrict__ v,
                                              const float* __restrict__ h,
                                              const int* __restrict__ rowptr,
                                              const int* __restrict__ colidx,
                                              const float* __restrict__ dinv,
                                              bf16* __restrict__ outB,
                                              float* __restrict__ outF,
                                              int final_it) {
    int r = (blockIdx.x * 256 + threadIdx.x) >> 6;  // one wave per row
    int lane = threadIdx.x & 63;
    if (r >= N_NODES || lane >= NCLASS) return;
    int s = rowptr[r], e = rowptr[r + 1];
    float a[8];
    a[0] = (float)v[(size_t)r * 64 + lane];  // self-loop
#pragma unroll
    for (int u = 1; u < 8; u++) a[u] = 0.f;
    int i = s;
    for (; i + 8 <= e; i += 8) {
        int c[8];
#pragma unroll
        for (int u = 0; u < 8; u++) c[u] = colidx[i + u];
#pragma unroll
        for (int u = 0; u < 8; u++) a[u] += (float)v[(size_t)c[u] * 64 + lane];
    }
    for (; i < e; i++) a[0] += (float)v[(size_t)colidx[i] * 64 + lane];
    float acc = ((a[0] + a[1]) + (a[2] + a[3])) + ((a[4] + a[5]) + (a[6] + a[7]));
    float res = 0.5f * dinv[r] * acc + 0.5f * h[(size_t)r * NCLASS + lane];
    if (final_it) outF[(size_t)r * NCLASS + lane] = res;
    else outB[(size_t)r * 64 + lane] = (bf16)res;
}

// ---------------- launch ----------------

static inline size_t align256(size_t x) { return (x + 255) & ~(size_t)255; }

extern "C" void kernel_launch(void* const* d_in, const int* in_sizes, int n_in,
                              void* d_out, int out_size, void* d_ws, size_t ws_size,
                              hipStream_t stream) {
    const float* x  = (const float*)d_in[0];
    const int*   ei = (const int*)d_in[1];
    const float* W1 = (const float*)d_in[2];
    const float* b1 = (const float*)d_in[3];
    const float* W2 = (const float*)d_in[4];
    const float* b2 = (const float*)d_in[5];
    const float* W3 = (const float*)d_in[6];
    const float* b3 = (const float*)d_in[7];
    float* out = (float*)d_out;
    const int* rows = ei;
    const int* cols = ei + N_EDGES;

    // workspace carve: fixed-size tail first, hid1/hid2 take the remainder
    char* p = (char*)d_ws;
    float* h   = (float*)p;   p += align256((size_t)N_NODES * NCLASS * 4); // 16 MB
    bf16* hpad = (bf16*)p;    p += align256((size_t)N_NODES * 64 * 2);     // 12.8 MB
    bf16* W1b  = (bf16*)p;    p += align256((size_t)NHID * NFEAT * 2);
    bf16* W2b  = (bf16*)p;    p += align256((size_t)NHID * NHID * 2);
    bf16* W3p  = (bf16*)p;    p += align256((size_t)64 * NHID * 2);
    float* b3p = (float*)p;   p += align256(64 * 4);
    int* cnt    = (int*)p;    p += align256((size_t)NPAD * 4);
    int* rowptr = (int*)p;    p += align256((size_t)(NPAD + 1) * 4);
    int* cursor = (int*)p;    p += align256((size_t)N_NODES * 4);
    int* colidx = (int*)p;    p += align256((size_t)N_EDGES * 4);
    int* bsum   = (int*)p;    p += align256(512 * 4);
    float* dinv = (float*)p;  p += align256((size_t)N_NODES * 4);

    size_t used = (size_t)(p - (char*)d_ws);
    size_t remain = (ws_size > used) ? (ws_size - used) : 0;
    // rows per MLP chunk: fill remaining ws with two [chunk,256] bf16 buffers
    long long cr = (long long)(remain / 2 / (NHID * 2));
    cr = (cr / 128) * 128;
    if (cr > N_NODES) cr = ((N_NODES + 127) / 128) * 128;
    if (cr < 25088) cr = 25088;  // R2 proved this fits; also needed for v0/v1 alias
    int chunk = (int)cr;
    bf16* hid1 = (bf16*)p;
    bf16* hid2 = hid1 + (size_t)chunk * NHID;
    // v0/v1 alias hid1/hid2 (dead after MLP finishes); need N_NODES*64 bf16 each
    bf16* v0 = hid1;
    bf16* v1 = hid2;

    // CSR build
    init_cnt<<<NPAD / 256, 256, 0, stream>>>(cnt);
    count_edges<<<(N_EDGES + 255) / 256, 256, 0, stream>>>(rows, cnt);
    reduce_blocks<<<NB, 256, 0, stream>>>(cnt, bsum);
    scan_bsums<<<1, 512, 0, stream>>>(bsum);
    scan_write<<<NB, 256, 0, stream>>>(cnt, bsum, rowptr, cursor, dinv);
    // 4-pass row-range scatter: writes stay L2-resident per pass
    for (int pass = 0; pass < 4; pass++) {
        int lo = pass * 25000, hi = (pass == 3) ? N_NODES : (pass + 1) * 25000;
        scatter_edges_range<<<(N_EDGES + 255) / 256, 256, 0, stream>>>(
            rows, cols, cursor, colidx, lo, hi);
    }

    // weight conversion
    cvt_f2b<<<(NHID * NFEAT + 255) / 256, 256, 0, stream>>>(W1, W1b, NHID * NFEAT);
    cvt_f2b<<<(NHID * NHID + 255) / 256, 256, 0, stream>>>(W2, W2b, NHID * NHID);
    pad_w3<<<(64 * NHID) / 256, 256, 0, stream>>>(W3, b3, W3p, b3p);

    // MLP in row chunks
    for (int off = 0; off < N_NODES; off += chunk) {
        int Mc = (N_NODES - off < chunk) ? (N_NODES - off) : chunk;
        int gy = (Mc + 127) / 128;
        dim3 g12(2, gy);
        gemm_mfma<128, float, true, 0><<<g12, 256, 0, stream>>>(
            x + (size_t)off * NFEAT, W1b, b1, hid1, nullptr, nullptr, Mc, NFEAT, NHID);
        gemm_mfma<128, bf16, true, 0><<<g12, 256, 0, stream>>>(
            hid1, W2b, b2, hid2, nullptr, nullptr, Mc, NHID, NHID);
        dim3 g3(1, gy);
        gemm_mfma<64, bf16, false, 1><<<g3, 256, 0, stream>>>(
            hid2, W3p, b3p, nullptr, h + (size_t)off * NCLASS, hpad + (size_t)off * 64,
            Mc, NHID, 64);
    }

    // 10 power iterations (v stored bf16, rows padded to 64 = one 128B line)
    const bf16* src = hpad;
    for (int it = 0; it < 10; it++) {
        int fin = (it == 9);
        bf16* dst = (it & 1) ? v1 : v0;
        spmm_b<<<(N_NODES * 64 + 255) / 256, 256, 0, stream>>>(
            src, h, rowptr, colidx, dinv, dst, out, fin);
        src = dst;
    }
}